// Round 13
// baseline (206.528 us; speedup 1.0000x reference)
//
#include <hip/hip_runtime.h>
#include <hip/hip_bf16.h>

typedef __attribute__((ext_vector_type(4))) float f32x4;
typedef __attribute__((ext_vector_type(8))) short bf16x8;

#define SBAR __builtin_amdgcn_sched_barrier(0)

// fp32 -> bf16 bits, round-to-nearest-even
__device__ __forceinline__ unsigned short f2bf(float f) {
  unsigned int u = __builtin_bit_cast(unsigned int, f);
  u += 0x7FFFu + ((u >> 16) & 1u);
  return (unsigned short)(u >> 16);
}

// async 16B global -> LDS (wave-uniform LDS base + lane*16 hardware layout)
__device__ __forceinline__ void async_ld16(const void* g, void* l) {
  __builtin_amdgcn_global_load_lds(
      (__attribute__((address_space(1))) void*)g,
      (__attribute__((address_space(3))) void*)l, 16, 0, 0);
}

// ---------------------------------------------------------------------------
// Weight packing: fragment-order bf16 (same lane-mapping serves A-op & B-op).
// ---------------------------------------------------------------------------
__global__ __launch_bounds__(256) void pack_AB(
    const float* __restrict__ Af, const float* __restrict__ Am,
    const float* __restrict__ As, const float* __restrict__ Bf,
    const float* __restrict__ Bm, const float* __restrict__ Bs,
    short* __restrict__ Apack, short* __restrict__ Bpack)
{
  unsigned idx = blockIdx.x * 256u + threadIdx.x;     // < 786432
  if (idx < 393216u) {
    unsigned j = idx & 7u, lane = (idx >> 3) & 63u, rest = idx >> 9;
    unsigned t = rest % 6u, chunk = rest / 6u;
    unsigned k = chunk * 32u + ((lane >> 4) << 3) + j;
    unsigned c = t * 16u + (lane & 15u);
    float v;
    if (c < 32u)      v = Af[k * 32u + c];
    else if (c < 64u) v = Am[k * 32u + (c - 32u)];
    else              v = As[k * 32u + (c - 64u)];
    Apack[idx] = (short)f2bf(v);
  } else {
    unsigned i2 = idx - 393216u;
    unsigned j = i2 & 7u, lane = (i2 >> 3) & 63u, rest = i2 >> 9;
    unsigned nt = rest & 255u, kc = rest >> 8;
    unsigned k = kc * 32u + ((lane >> 4) << 3) + j;
    unsigned n = nt * 16u + (lane & 15u);
    float v;
    if (k < 32u)      v = Bf[k * 4096u + n];
    else if (k < 64u) v = Bm[(k - 32u) * 4096u + n];
    else              v = Bs[(k - 64u) * 4096u + n];
    Bpack[i2] = (short)f2bf(v * 0.03125f);            // fold SCALE = 1/32
  }
}

// ---------------------------------------------------------------------------
// Stage 1 (r8 champion, verbatim): hg fragments = x @ Apack. 1024 blocks
// (16 rows) x 4 waves. Contiguous gload_lds staging, double buffer with RAW
// s_barrier + counted s_waitcnt vmcnt(4).
// ---------------------------------------------------------------------------
__global__ __launch_bounds__(256, 4) void lora_stage1(
    const float* __restrict__ x, const short* __restrict__ Apack,
    short* __restrict__ hg)
{
  const int rb  = blockIdx.x;            // 16-row tile
  const int tid = threadIdx.x;
  const int w = tid >> 6, l = tid & 63;
  const int lm = l & 15, lk = l >> 4;
  const size_t rowbase = (size_t)rb * 16;

  __shared__ __align__(16) float smem[8192];   // 32 KiB: xs dbuf -> hp reuse

  f32x4 acc[6];
#pragma unroll
  for (int t = 0; t < 6; ++t) acc[t] = (f32x4){0.f, 0.f, 0.f, 0.f};

  auto stage = [&](int s, int b) {
    float* base = smem + b * 4096;
    const float* gx = x + rowbase * 4096 + s * 256;
#pragma unroll
    for (int i = 0; i < 4; ++i) {
      int r = w * 4 + i;
      async_ld16(gx + (size_t)r * 4096 + ((l ^ (r & 7)) << 2), base + r * 256);
    }
  };

  auto consume = [&](int st) {
    const float* rowp = smem + (st & 1) * 4096 + lm * 256;
    const int sw = lm & 7;
#pragma unroll
    for (int p = 0; p < 2; ++p) {
      int ksub = w * 2 + p;
      int b0 = ksub * 8 + lk * 2;
      f32x4 xa = *(const f32x4*)(rowp + (((b0)     ^ sw) << 2));
      f32x4 xb = *(const f32x4*)(rowp + (((b0 + 1) ^ sw) << 2));
      bf16x8 xf;
      xf[0] = (short)f2bf(xa[0]); xf[1] = (short)f2bf(xa[1]);
      xf[2] = (short)f2bf(xa[2]); xf[3] = (short)f2bf(xa[3]);
      xf[4] = (short)f2bf(xb[0]); xf[5] = (short)f2bf(xb[1]);
      xf[6] = (short)f2bf(xb[2]); xf[7] = (short)f2bf(xb[3]);
      int kchunk = st * 8 + ksub;
#pragma unroll
      for (int t = 0; t < 6; ++t) {
        bf16x8 av = *(const bf16x8*)(Apack + ((size_t)kchunk * 6 + t) * 512 + l * 8);
        acc[t] = __builtin_amdgcn_mfma_f32_16x16x32_bf16(xf, av, acc[t], 0, 0, 0);
      }
    }
  };

  stage(0, 0);
#pragma unroll 1
  for (int st = 0; st < 15; ++st) {
    stage(st + 1, (st + 1) & 1);         // issue next step FIRST (FIFO shape)
    SBAR;
    asm volatile("s_waitcnt vmcnt(4)" ::: "memory");   // oldest step landed
    SBAR;
    __builtin_amdgcn_s_barrier();        // raw barrier: NO vmcnt(0) drain
    SBAR;
    consume(st);
    SBAR;
    __builtin_amdgcn_s_barrier();        // reads done before buf reuse
    SBAR;
  }
  asm volatile("s_waitcnt vmcnt(0)" ::: "memory");
  SBAR;
  __builtin_amdgcn_s_barrier();
  SBAR;
  consume(15);
  __syncthreads();                       // full drain before smem reuse

  // partials: hp[w][16][100] in reused smem
  {
    float* hpw = smem + w * 1600;
#pragma unroll
    for (int t = 0; t < 6; ++t)
#pragma unroll
      for (int q = 0; q < 4; ++q)
        hpw[(lk * 4 + q) * 100 + t * 16 + lm] = acc[t][q];
  }
  __syncthreads();

  // reduce 4 wave-partials -> bf16 fragments -> global hg[tile][kc][lane][8]
  if (tid < 192) {
    int r = tid / 12, c8 = tid % 12;     // row 0..15, col-group of 8
    const float* p = smem + r * 100 + c8 * 8;
    f32x4 s0 = *(const f32x4*)(p)        + *(const f32x4*)(p + 1600)
             + *(const f32x4*)(p + 3200) + *(const f32x4*)(p + 4800);
    f32x4 s1 = *(const f32x4*)(p + 4)    + *(const f32x4*)(p + 1604)
             + *(const f32x4*)(p + 3204) + *(const f32x4*)(p + 4804);
    bf16x8 o;
    o[0] = (short)f2bf(s0[0]); o[1] = (short)f2bf(s0[1]);
    o[2] = (short)f2bf(s0[2]); o[3] = (short)f2bf(s0[3]);
    o[4] = (short)f2bf(s1[0]); o[5] = (short)f2bf(s1[1]);
    o[6] = (short)f2bf(s1[2]); o[7] = (short)f2bf(s1[3]);
    *(bf16x8*)(hg + ((size_t)rb * 192 + (c8 >> 2) * 64 + (c8 & 3) * 16 + r) * 8) = o;
  }
}

// ---------------------------------------------------------------------------
// Stage 2 (r8 champion, verbatim): B-fragments resident in registers,
// iterate over row-tiles. Swapped mfma operands; one dwordx4 store per tile.
// ---------------------------------------------------------------------------
__global__ __launch_bounds__(256, 4) void lora_stage2(
    const short* __restrict__ hg, const short* __restrict__ Bpack,
    float* __restrict__ out)
{
  const int bid = blockIdx.x;
  const int rs = bid >> 4;               // row-slab: tiles rs*8 .. +8
  const int cb = bid & 15;               // 256-col group
  const int tid = threadIdx.x;
  const int w = tid >> 6, l = tid & 63;
  const int lm = l & 15, lk = l >> 4;
  const int nt0 = cb * 16 + w * 4;       // wave's 4 n-tiles

  // persistent B fragments: 4 nt x 3 kc (48 VGPR)
  bf16x8 bf[4][3];
#pragma unroll
  for (int n = 0; n < 4; ++n)
#pragma unroll
    for (int kc = 0; kc < 3; ++kc)
      bf[n][kc] = *(const bf16x8*)(Bpack + ((size_t)(kc * 256 + nt0 + n)) * 512 + l * 8);

#pragma unroll 2
  for (int it = 0; it < 8; ++it) {
    const int tile = rs * 8 + it;
    const short* hp = hg + (size_t)tile * 1536 + (size_t)l * 8;  // 192*8 shorts/tile
    bf16x8 hf0 = *(const bf16x8*)(hp);
    bf16x8 hf1 = *(const bf16x8*)(hp + 512);
    bf16x8 hf2 = *(const bf16x8*)(hp + 1024);
    float* orow = out + ((size_t)tile * 16 + lm) * 4096;
#pragma unroll
    for (int n = 0; n < 4; ++n) {
      f32x4 a = {0.f, 0.f, 0.f, 0.f};
      a = __builtin_amdgcn_mfma_f32_16x16x32_bf16(bf[n][0], hf0, a, 0, 0, 0);
      a = __builtin_amdgcn_mfma_f32_16x16x32_bf16(bf[n][1], hf1, a, 0, 0, 0);
      a = __builtin_amdgcn_mfma_f32_16x16x32_bf16(bf[n][2], hf2, a, 0, 0, 0);
      *(f32x4*)(orow + (nt0 + n) * 16 + lk * 4) = a;
    }
  }
}

extern "C" void kernel_launch(void* const* d_in, const int* in_sizes, int n_in,
                              void* d_out, int out_size, void* d_ws, size_t ws_size,
                              hipStream_t stream) {
  const float* x  = (const float*)d_in[0];
  const float* Af = (const float*)d_in[1];
  const float* Bf = (const float*)d_in[2];
  const float* Am = (const float*)d_in[3];
  const float* Bm = (const float*)d_in[4];
  const float* As = (const float*)d_in[5];
  const float* Bs = (const float*)d_in[6];
  float* out = (float*)d_out;

  char* ws = (char*)d_ws;
  short* Apack = (short*)ws;                    // 786432 B
  short* Bpack = (short*)(ws + 786432);         // 786432 B
  short* hg    = (short*)(ws + 2 * 786432);     // 1024*192*8*2 = 3145728 B

  hipLaunchKernelGGL(pack_AB, dim3(3072), dim3(256), 0, stream,
                     Af, Am, As, Bf, Bm, Bs, Apack, Bpack);
  // ATTRIBUTION PROBE: stage1 launched TWICE (idempotent -- rewrites the same
  // hg). s1_duration = total_this_round - 141.4us (the single-launch champion).
  hipLaunchKernelGGL(lora_stage1, dim3(1024), dim3(256), 0, stream, x, Apack, hg);
  hipLaunchKernelGGL(lora_stage1, dim3(1024), dim3(256), 0, stream, x, Apack, hg);
  hipLaunchKernelGGL(lora_stage2, dim3(2048), dim3(256), 0, stream, hg, Bpack, out);
}

// Round 14
// 151.280 us; speedup vs baseline: 1.3652x; 1.3652x over previous
//
#include <hip/hip_runtime.h>
#include <hip/hip_bf16.h>

typedef __attribute__((ext_vector_type(4))) float f32x4;
typedef __attribute__((ext_vector_type(8))) short bf16x8;

#define SBAR __builtin_amdgcn_sched_barrier(0)

// fp32 -> bf16 bits, round-to-nearest-even
__device__ __forceinline__ unsigned short f2bf(float f) {
  unsigned int u = __builtin_bit_cast(unsigned int, f);
  u += 0x7FFFu + ((u >> 16) & 1u);
  return (unsigned short)(u >> 16);
}

// async 16B global -> LDS (wave-uniform LDS base + lane*16 hardware layout)
__device__ __forceinline__ void async_ld16(const void* g, void* l) {
  __builtin_amdgcn_global_load_lds(
      (__attribute__((address_space(1))) void*)g,
      (__attribute__((address_space(3))) void*)l, 16, 0, 0);
}

// ---------------------------------------------------------------------------
// Weight packing: fragment-order bf16 (same lane-mapping serves A-op & B-op).
// ---------------------------------------------------------------------------
__global__ __launch_bounds__(256) void pack_AB(
    const float* __restrict__ Af, const float* __restrict__ Am,
    const float* __restrict__ As, const float* __restrict__ Bf,
    const float* __restrict__ Bm, const float* __restrict__ Bs,
    short* __restrict__ Apack, short* __restrict__ Bpack)
{
  unsigned idx = blockIdx.x * 256u + threadIdx.x;     // < 786432
  if (idx < 393216u) {
    unsigned j = idx & 7u, lane = (idx >> 3) & 63u, rest = idx >> 9;
    unsigned t = rest % 6u, chunk = rest / 6u;
    unsigned k = chunk * 32u + ((lane >> 4) << 3) + j;
    unsigned c = t * 16u + (lane & 15u);
    float v;
    if (c < 32u)      v = Af[k * 32u + c];
    else if (c < 64u) v = Am[k * 32u + (c - 32u)];
    else              v = As[k * 32u + (c - 64u)];
    Apack[idx] = (short)f2bf(v);
  } else {
    unsigned i2 = idx - 393216u;
    unsigned j = i2 & 7u, lane = (i2 >> 3) & 63u, rest = i2 >> 9;
    unsigned nt = rest & 255u, kc = rest >> 8;
    unsigned k = kc * 32u + ((lane >> 4) << 3) + j;
    unsigned n = nt * 16u + (lane & 15u);
    float v;
    if (k < 32u)      v = Bf[k * 4096u + n];
    else if (k < 64u) v = Bm[(k - 32u) * 4096u + n];
    else              v = Bs[(k - 64u) * 4096u + n];
    Bpack[i2] = (short)f2bf(v * 0.03125f);            // fold SCALE = 1/32
  }
}

// ---------------------------------------------------------------------------
// Stage 1 (r8 structure, deepened): hg fragments = x @ Apack. 1024 blocks
// (16 rows) x 4 waves. 3 staging buffers x 16 KB, TWO steps in flight
// (s_waitcnt vmcnt(8) = own 8 newer DMAs outstanding), raw s_barrier pair
// per step. 3 blocks/CU -> 96 KB/CU HBM reads in flight (was 64).
// ---------------------------------------------------------------------------
__global__ __launch_bounds__(256, 3) void lora_stage1(
    const float* __restrict__ x, const short* __restrict__ Apack,
    short* __restrict__ hg)
{
  const int rb  = blockIdx.x;            // 16-row tile
  const int tid = threadIdx.x;
  const int w = tid >> 6, l = tid & 63;
  const int lm = l & 15, lk = l >> 4;
  const size_t rowbase = (size_t)rb * 16;

  __shared__ __align__(16) float smem[12288];  // 48 KiB: 3 bufs -> hp reuse

  f32x4 acc[6];
#pragma unroll
  for (int t = 0; t < 6; ++t) acc[t] = (f32x4){0.f, 0.f, 0.f, 0.f};

  auto stage = [&](int s, int b) {
    float* base = smem + b * 4096;
    const float* gx = x + rowbase * 4096 + s * 256;
#pragma unroll
    for (int i = 0; i < 4; ++i) {
      int r = w * 4 + i;
      async_ld16(gx + (size_t)r * 4096 + ((l ^ (r & 7)) << 2), base + r * 256);
    }
  };

  auto consume = [&](int st, int b) {
    const float* rowp = smem + b * 4096 + lm * 256;
    const int sw = lm & 7;
#pragma unroll
    for (int p = 0; p < 2; ++p) {
      int ksub = w * 2 + p;
      int b0 = ksub * 8 + lk * 2;
      f32x4 xa = *(const f32x4*)(rowp + (((b0)     ^ sw) << 2));
      f32x4 xb = *(const f32x4*)(rowp + (((b0 + 1) ^ sw) << 2));
      bf16x8 xf;
      xf[0] = (short)f2bf(xa[0]); xf[1] = (short)f2bf(xa[1]);
      xf[2] = (short)f2bf(xa[2]); xf[3] = (short)f2bf(xa[3]);
      xf[4] = (short)f2bf(xb[0]); xf[5] = (short)f2bf(xb[1]);
      xf[6] = (short)f2bf(xb[2]); xf[7] = (short)f2bf(xb[3]);
      int kchunk = st * 8 + ksub;
#pragma unroll
      for (int t = 0; t < 6; ++t) {
        bf16x8 av = *(const bf16x8*)(Apack + ((size_t)kchunk * 6 + t) * 512 + l * 8);
        acc[t] = __builtin_amdgcn_mfma_f32_16x16x32_bf16(xf, av, acc[t], 0, 0, 0);
      }
    }
  };

  stage(0, 0);
  stage(1, 1);                           // 8 DMAs outstanding / wave
#pragma unroll 1
  for (int st = 0; st < 14; ++st) {
    stage(st + 2, (st + 2) % 3);         // keep 2 steps in flight
    SBAR;
    asm volatile("s_waitcnt vmcnt(8)" ::: "memory");   // step st landed
    SBAR;
    __builtin_amdgcn_s_barrier();        // raw: no vmcnt(0) drain
    SBAR;
    consume(st, st % 3);
    SBAR;
    __builtin_amdgcn_s_barrier();        // reads done before buf reuse
    SBAR;
  }
  asm volatile("s_waitcnt vmcnt(4)" ::: "memory");
  SBAR;
  __builtin_amdgcn_s_barrier();
  SBAR;
  consume(14, 14 % 3);
  SBAR;
  __builtin_amdgcn_s_barrier();
  SBAR;
  asm volatile("s_waitcnt vmcnt(0)" ::: "memory");
  SBAR;
  __builtin_amdgcn_s_barrier();
  SBAR;
  consume(15, 15 % 3);
  __syncthreads();                       // full drain before smem reuse

  // partials: hp[w][16][100] in reused smem
  {
    float* hpw = smem + w * 1600;
#pragma unroll
    for (int t = 0; t < 6; ++t)
#pragma unroll
      for (int q = 0; q < 4; ++q)
        hpw[(lk * 4 + q) * 100 + t * 16 + lm] = acc[t][q];
  }
  __syncthreads();

  // reduce 4 wave-partials -> bf16 fragments -> global hg[tile][kc][lane][8]
  if (tid < 192) {
    int r = tid / 12, c8 = tid % 12;     // row 0..15, col-group of 8
    const float* p = smem + r * 100 + c8 * 8;
    f32x4 s0 = *(const f32x4*)(p)        + *(const f32x4*)(p + 1600)
             + *(const f32x4*)(p + 3200) + *(const f32x4*)(p + 4800);
    f32x4 s1 = *(const f32x4*)(p + 4)    + *(const f32x4*)(p + 1604)
             + *(const f32x4*)(p + 3204) + *(const f32x4*)(p + 4804);
    bf16x8 o;
    o[0] = (short)f2bf(s0[0]); o[1] = (short)f2bf(s0[1]);
    o[2] = (short)f2bf(s0[2]); o[3] = (short)f2bf(s0[3]);
    o[4] = (short)f2bf(s1[0]); o[5] = (short)f2bf(s1[1]);
    o[6] = (short)f2bf(s1[2]); o[7] = (short)f2bf(s1[3]);
    *(bf16x8*)(hg + ((size_t)rb * 192 + (c8 >> 2) * 64 + (c8 & 3) * 16 + r) * 8) = o;
  }
}

// ---------------------------------------------------------------------------
// Stage 2 (r8 structure + wave-private transpose): B-fragments resident,
// iterate row-tiles, NO barriers. D fragments bounce through a 4.3 KB
// wave-private LDS tile (in-order LDS pipe + lgkmcnt(0), no s_barrier) so
// each store instruction writes 4 rows x 256 B CONTIGUOUS (r8: 16 x 64 B).
// ---------------------------------------------------------------------------
__global__ __launch_bounds__(256, 4) void lora_stage2(
    const short* __restrict__ hg, const short* __restrict__ Bpack,
    float* __restrict__ out)
{
  const int bid = blockIdx.x;
  const int rs = bid >> 4;               // row-slab: tiles rs*8 .. +8
  const int cb = bid & 15;               // 256-col group
  const int tid = threadIdx.x;
  const int w = tid >> 6, l = tid & 63;
  const int lm = l & 15, lk = l >> 4;
  const int nt0 = cb * 16 + w * 4;       // wave's 4 n-tiles (64 cols)

  __shared__ __align__(16) float trans[4][16 * 68 + 8]; // per-wave transpose

  float* tw = &trans[w][0];
  const int rrow = l >> 4;               // read-back: row group 0..3
  const int rcol = (l & 15) * 4;         // floats 0..60

  // persistent B fragments: 4 nt x 3 kc (48 VGPR)
  bf16x8 bf[4][3];
#pragma unroll
  for (int n = 0; n < 4; ++n)
#pragma unroll
    for (int kc = 0; kc < 3; ++kc)
      bf[n][kc] = *(const bf16x8*)(Bpack + ((size_t)(kc * 256 + nt0 + n)) * 512 + l * 8);

#pragma unroll 2
  for (int it = 0; it < 8; ++it) {
    const int tile = rs * 8 + it;
    const short* hp = hg + (size_t)tile * 1536 + (size_t)l * 8;
    bf16x8 hf0 = *(const bf16x8*)(hp);
    bf16x8 hf1 = *(const bf16x8*)(hp + 512);
    bf16x8 hf2 = *(const bf16x8*)(hp + 1024);
    // D layout (swapped operands): row = lm, cols = (w*4+n)*16 + lk*4 + q
#pragma unroll
    for (int n = 0; n < 4; ++n) {
      f32x4 a = {0.f, 0.f, 0.f, 0.f};
      a = __builtin_amdgcn_mfma_f32_16x16x32_bf16(bf[n][0], hf0, a, 0, 0, 0);
      a = __builtin_amdgcn_mfma_f32_16x16x32_bf16(bf[n][1], hf1, a, 0, 0, 0);
      a = __builtin_amdgcn_mfma_f32_16x16x32_bf16(bf[n][2], hf2, a, 0, 0, 0);
      *(f32x4*)&tw[lm * 68 + n * 16 + lk * 4] = a;    // wave-private
    }
    SBAR;
    asm volatile("s_waitcnt lgkmcnt(0)" ::: "memory"); // writes visible (same wave)
    SBAR;
    // read back row-linear; store 4 rows x 256 B contiguous per instruction
    float* obase = out + ((size_t)tile * 16) * 4096 + nt0 * 16;
#pragma unroll
    for (int i = 0; i < 4; ++i) {
      int row = i * 4 + rrow;
      f32x4 v = *(const f32x4*)&tw[row * 68 + rcol];
      *(f32x4*)(obase + (size_t)row * 4096 + rcol) = v;
    }
    SBAR;  // in-order LDS pipe: next it's ds_writes queue after these reads
  }
}

extern "C" void kernel_launch(void* const* d_in, const int* in_sizes, int n_in,
                              void* d_out, int out_size, void* d_ws, size_t ws_size,
                              hipStream_t stream) {
  const float* x  = (const float*)d_in[0];
  const float* Af = (const float*)d_in[1];
  const float* Bf = (const float*)d_in[2];
  const float* Am = (const float*)d_in[3];
  const float* Bm = (const float*)d_in[4];
  const float* As = (const float*)d_in[5];
  const float* Bs = (const float*)d_in[6];
  float* out = (float*)d_out;

  char* ws = (char*)d_ws;
  short* Apack = (short*)ws;                    // 786432 B
  short* Bpack = (short*)(ws + 786432);         // 786432 B
  short* hg    = (short*)(ws + 2 * 786432);     // 1024*192*8*2 = 3145728 B

  hipLaunchKernelGGL(pack_AB, dim3(3072), dim3(256), 0, stream,
                     Af, Am, As, Bf, Bm, Bs, Apack, Bpack);
  hipLaunchKernelGGL(lora_stage1, dim3(1024), dim3(256), 0, stream, x, Apack, hg);
  hipLaunchKernelGGL(lora_stage2, dim3(2048), dim3(256), 0, stream, hg, Bpack, out);
}